// Round 13
// baseline (179.399 us; speedup 1.0000x reference)
//
#include <hip/hip_runtime.h>
#include <hip/hip_bf16.h>

typedef unsigned short u16;
typedef unsigned int u32;
typedef __bf16 bf16x8 __attribute__((ext_vector_type(8)));
typedef float f32x4 __attribute__((ext_vector_type(4)));
typedef u16 u16x8 __attribute__((ext_vector_type(8)));
typedef u32 u32x2 __attribute__((ext_vector_type(2)));

#define S_LEN 2048
#define DMODEL 512
#define NHEAD 8
#define DHEAD 64
// log2(e); Q is pre-scaled by 0.125*LOG2E so softmax runs in exp2 domain.
#define QSCALE 0.1803368801111204f
#define MASKC 1.4426950409e9f
#define RESCALE_THR 8.0f

static __device__ __forceinline__ u16 f2bf(float f) {
    union { float f; unsigned u; } cv; cv.f = f;
    unsigned u = cv.u;
    return (u16)((u + 0x7fffu + ((u >> 16) & 1u)) >> 16);  // RNE
}
static __device__ __forceinline__ u32 pk2bf(float a, float b) {
    union { __hip_bfloat162 h; u32 u; } cv;
    float2 f2; f2.x = a; f2.y = b;
    cv.h = __float22bfloat162_rn(f2);
    return cv.u;
}
static __device__ __forceinline__ bf16x8 ld8(const u16* p) {
    return *(const bf16x8*)p;
}
static __device__ __forceinline__ float fmax3(float a, float b, float c) {
    return __builtin_fmaxf(__builtin_fmaxf(a, b), c);  // clang fuses to v_max3_f32
}
// async global->LDS, 16B per lane. LDS dest MUST be wave-uniform base + lane*16 (m104);
// swizzles are applied on the GLOBAL source address instead (m173 pattern).
static __device__ __forceinline__ void gll16(const void* g, void* l) {
    __builtin_amdgcn_global_load_lds(
        (const __attribute__((address_space(1))) void*)g,
        (__attribute__((address_space(3))) void*)l, 16, 0, 0);
}

// ---------------- fused prep: qkv fp32->bf16 cvt | weight transpose->bf16 | mask flags ----
// grid.x partition: [0,3072) cvt, [3072,4096) transpose_w, [4096,6144) mask flags. 256 thr.
__global__ __launch_bounds__(256) void prep_kernel(
    const float* __restrict__ q, const float* __restrict__ k, const float* __restrict__ v,
    const float* __restrict__ w0, const float* __restrict__ w1,
    const float* __restrict__ w2, const float* __restrict__ w3,
    const float* __restrict__ mask,
    u16* __restrict__ Aqkv, u16* __restrict__ wtall, int* __restrict__ flags) {
    const int p = blockIdx.x;
    const int tid = threadIdx.x;
    __shared__ float t[32][33];
    __shared__ int wred[4];
    if (p < 3072) {
        const int z = p >> 10, px = p & 1023;
        const float* in = (z == 0) ? q : (z == 1) ? k : v;
        u16* o = Aqkv + (long)z * 2097152;
        long i = ((long)px * 256 + tid) * 8;
        f32x4 a = *(const f32x4*)(in + i);
        f32x4 b = *(const f32x4*)(in + i + 4);
        u16x8 r;
#pragma unroll
        for (int j = 0; j < 4; ++j) { r[j] = f2bf(a[j]); r[4 + j] = f2bf(b[j]); }
        *(u16x8*)(o + i) = r;
    } else if (p < 4096) {
        // W (512x512 fp32) -> Wt bf16 (N x K). slot order in wtall: [wo, wq, wk, wv]
        const int p2 = p - 3072;
        const int z = p2 >> 8, rem = p2 & 255, by = rem >> 4, bx = rem & 15;
        const float* in = (z == 0) ? w0 : (z == 1) ? w1 : (z == 2) ? w2 : w3;
        u16* o = wtall + (long)(((z + 1) & 3)) * 262144;
        const int tx = tid & 31, ty = tid >> 5;
#pragma unroll
        for (int i = 0; i < 4; ++i)
            t[ty + 8 * i][tx] = in[(by * 32 + ty + 8 * i) * DMODEL + bx * 32 + tx];
        __syncthreads();
#pragma unroll
        for (int i = 0; i < 4; ++i)
            o[(bx * 32 + ty + 8 * i) * DMODEL + by * 32 + tx] = f2bf(t[tx][ty + 8 * i]);
    } else {
        const int bid = p - 4096;  // 2*32*32
        const int b = bid >> 10, qt = (bid >> 5) & 31, kt = bid & 31;
        const int r = tid >> 2, cs = tid & 3;
        const float* mp = mask + ((long)(b * S_LEN + qt * 64 + r)) * S_LEN + kt * 64 + cs * 16;
        int nz = 0;
#pragma unroll
        for (int j = 0; j < 4; ++j) {
            f32x4 a = *(const f32x4*)(mp + j * 4);
            nz |= (a[0] != 0.f) | (a[1] != 0.f) | (a[2] != 0.f) | (a[3] != 0.f);
        }
        unsigned long long ball = __ballot(nz);
        if ((tid & 63) == 0) wred[tid >> 6] = (ball != 0ull) ? 1 : 0;
        __syncthreads();
        if (tid == 0) flags[bid] = wred[0] | wred[1] | wred[2] | wred[3];
    }
}

// ---------------- GEMM epilogue (shared) ----------------
template <bool F32OUT, int TM>
static __device__ __forceinline__ void store_c(f32x4 (&acc)[TM][2],
                                               const float* __restrict__ bias,
                                               void* __restrict__ Cp, float oscale,
                                               bool vtout, int m0, int n0, int cidx, int kg) {
    if (vtout) {
        // V-transposed: row = token (b,s), col = channel (h,d); packed 8B stores.
        const int bb = m0 >> 11;  // batch (tile never crosses the 2048 boundary)
#pragma unroll
        for (int j = 0; j < 2; ++j) {
            int col = n0 + j * 16 + cidx;
            float bv = bias[col];
            u16* vt = (u16*)Cp + (((long)(bb * 8 + (col >> 6))) * 64 + (col & 63)) * S_LEN;
#pragma unroll
            for (int i = 0; i < TM; ++i) {
                int s = (m0 + i * 16 + kg * 4) & (S_LEN - 1);
                u32x2 d;
                d[0] = pk2bf(acc[i][j][0] + bv, acc[i][j][1] + bv);
                d[1] = pk2bf(acc[i][j][2] + bv, acc[i][j][3] + bv);
                *(u32x2*)(vt + s) = d;
            }
        }
        return;
    }
#pragma unroll
    for (int j = 0; j < 2; ++j) {
        int col = n0 + j * 16 + cidx;
        float bv = bias[col];
#pragma unroll
        for (int i = 0; i < TM; ++i) {
#pragma unroll
            for (int r = 0; r < 4; ++r) {
                int row = m0 + i * 16 + kg * 4 + r;
                float val = (acc[i][j][r] + bv) * oscale;
                if (F32OUT) {
                    ((float*)Cp)[(long)row * DMODEL + col] = val;
                } else {
                    ((u16*)Cp)[(long)row * DMODEL + col] = f2bf(val);
                }
            }
        }
    }
}

// ---------------- LDS-staged double-buffered GEMM via global_load_lds ----------------
// C(4096x512) = A(4096x512,bf16) @ Wt^T + bias. Tile BM x 64, BK=32, 256 thr (4 waves 2x2).
// LDS linear [BM][32] (gll requires base+lane*16 dest); bank spread via GLOBAL-source
// XOR swizzle: LDS slot s of row r holds global chunk s ^ ((r>>1)&3); reader fetches
// chunk kg at slot kg ^ ((row>>1)&3) -> 2-way bank aliasing only (free, m136).
// Pipeline: issue gll(buf^1, t+1) -> compute buf (ds_read frags + MFMA) -> ONE barrier
// (its vmcnt drain completes the async loads).
template <int BM, bool F32OUT>
static __device__ __forceinline__ void gemm_lds(const u16* __restrict__ Ag,
                                                const u16* __restrict__ Wg,
                                                const float* __restrict__ bias,
                                                void* __restrict__ Cp, float oscale,
                                                bool vtout, int bx, int by) {
    constexpr int MR = BM / 32;        // M fragments per wave
    constexpr int ACH = BM * 4;        // 16B A-chunks per K-step
    constexpr int TOT = ACH + 256;     // + B-chunks
    constexpr int NCH = TOT / 256;     // 3 for BM=128, 2 for BM=64
    static_assert(TOT % 256 == 0, "chunk count must tile 256 threads");
    __shared__ __align__(16) u16 As[2][BM][32];
    __shared__ __align__(16) u16 Bs[2][64][32];

    const int tid = threadIdx.x;
    const int lane = tid & 63;
    const int wave = tid >> 6;
    const int wr = wave >> 1, wc = wave & 1;
    const int cidx = lane & 15;
    const int kg = lane >> 4;

    const u16* gsrc[NCH];
    u16* ldst[NCH][2];
#pragma unroll
    for (int j = 0; j < NCH; ++j) {
        int c = tid + 256 * j;
        if (c < ACH) {
            int r = c >> 2, s = c & 3;
            int sg = s ^ ((r >> 1) & 3);
            gsrc[j] = Ag + (long)(by * BM + r) * DMODEL + sg * 8;
            ldst[j][0] = &As[0][0][0] + c * 8;
            ldst[j][1] = &As[1][0][0] + c * 8;
        } else {
            int c2 = c - ACH;
            int r = c2 >> 2, s = c2 & 3;
            int sg = s ^ ((r >> 1) & 3);
            gsrc[j] = Wg + (long)(bx * 64 + r) * DMODEL + sg * 8;
            ldst[j][0] = &Bs[0][0][0] + c2 * 8;
            ldst[j][1] = &Bs[1][0][0] + c2 * 8;
        }
    }

    // prologue: tile0 -> LDS[0] (async)
#pragma unroll
    for (int j = 0; j < NCH; ++j) gll16(gsrc[j], ldst[j][0]);
    __syncthreads();

    const f32x4 fz = {0.f, 0.f, 0.f, 0.f};
    f32x4 acc[MR][2];
#pragma unroll
    for (int i = 0; i < MR; ++i)
#pragma unroll
        for (int j = 0; j < 2; ++j) acc[i][j] = fz;

    const int mw = wr * (BM / 2);
    const int nw = wc * 32;

#pragma unroll 2
    for (int t = 0; t < 16; ++t) {
        const int cur = t & 1;
        if (t + 1 < 16) {
#pragma unroll
            for (int j = 0; j < NCH; ++j) gll16(gsrc[j] + (t + 1) * 32, ldst[j][cur ^ 1]);
        }
        bf16x8 a[MR], b[2];
#pragma unroll
        for (int i = 0; i < MR; ++i) {
            int rl = mw + i * 16 + cidx;
            a[i] = ld8(&As[cur][rl][(kg ^ ((rl >> 1) & 3)) * 8]);
        }
#pragma unroll
        for (int j = 0; j < 2; ++j) {
            int rl = nw + j * 16 + cidx;
            b[j] = ld8(&Bs[cur][rl][(kg ^ ((rl >> 1) & 3)) * 8]);
        }
        __builtin_amdgcn_s_setprio(1);
#pragma unroll
        for (int i = 0; i < MR; ++i)
#pragma unroll
            for (int j = 0; j < 2; ++j)
                acc[i][j] = __builtin_amdgcn_mfma_f32_16x16x32_bf16(a[i], b[j], acc[i][j], 0, 0, 0);
        __builtin_amdgcn_s_setprio(0);
        __syncthreads();  // drains gll(buf^1) + completes reads of buf[cur]
    }

    store_c<F32OUT, MR>(acc, bias, Cp, oscale, vtout, by * BM + mw, bx * 64 + nw, cidx, kg);
}

// XCD-aware swizzle (T1): remap so the 8 bx-blocks sharing one A row-panel land on ONE XCD.
// Requires gridY % 8 == 0. Bijective.
static __device__ __forceinline__ void xcd_swizzle(int gridX, int gridY, int& bx, int& by) {
    const int flat = blockIdx.x + gridX * blockIdx.y;
    const int xcd = flat & 7;
    const int j = flat >> 3;
    by = xcd * (gridY >> 3) + j / gridX;
    bx = j % gridX;
}

// qkv: BM=128 -> grid (8,32,3) = 768 blocks = 3/CU, 24KB LDS.
__global__ __launch_bounds__(256) void qkv_gemm_kernel(
    const u16* __restrict__ Aqkv,
    const u16* __restrict__ wtall,
    const float* __restrict__ bq, const float* __restrict__ bk, const float* __restrict__ bv,
    u16* __restrict__ Q, u16* __restrict__ K, u16* __restrict__ Vt) {
    const u16* A = Aqkv + (long)blockIdx.z * 2097152;
    const u16* W = wtall + (long)(blockIdx.z + 1) * 262144;  // [wo, wq, wk, wv]
    const float* b;
    u16* C;
    float sc = 1.f;
    bool vt = false;
    if (blockIdx.z == 0) { b = bq; C = Q; sc = QSCALE; }  // fold 1/sqrt(DH)*log2e into Q
    else if (blockIdx.z == 1) { b = bk; C = K; }
    else { b = bv; C = Vt; vt = true; }
    int bx, by;
    xcd_swizzle(8, 32, bx, by);
    gemm_lds<128, false>(A, W, b, C, sc, vt, bx, by);
}

// out: BM=64 -> grid (8,64) = 512 blocks = 2/CU, 16KB LDS.
__global__ __launch_bounds__(256) void out_gemm_kernel(const u16* __restrict__ A,
                                                       const u16* __restrict__ Wt,
                                                       const float* __restrict__ bias,
                                                       float* __restrict__ C) {
    int bx, by;
    xcd_swizzle(8, 64, bx, by);
    gemm_lds<64, true>(A, Wt, bias, C, 1.f, false, bx, by);
}

// ---------------- flash attention, S^T formulation ----------------
// v8: 2-wave blocks (32 q-rows), grid (64,16) = 1024 blocks = 4 independent blocks/CU
// (vs 2 before) — attacks the ~45% no-issue fraction (MfmaUtil 17 + VALU 38, occ 17%):
// independent barriers interleave where 2 lockstep blocks couldn't. Per-wave compute
// code identical (wave owns 16 q-rows). Staging: 128 thr x 8 gll/tile, LDS 36KB.
__global__ __launch_bounds__(128) void attn_kernel(const u16* __restrict__ Q,
                                                   const u16* __restrict__ K,
                                                   const u16* __restrict__ Vt,
                                                   const float* __restrict__ mask,
                                                   const int* __restrict__ flags,
                                                   u16* __restrict__ Ab) {
    const int tid = threadIdx.x;
    const int lane = tid & 63;
    const int wave = tid >> 6;  // 0..1
    const int cidx = lane & 15;   // q-row (QK^T B-operand col / PV B-col); d-row for V A-frag
    const int kg = lane >> 4;
    // XCD-aware remap: XCD j gets F in [128j,128j+128) = all 64 q-tiles of bh pair {2j,2j+1}.
    const int flat = blockIdx.x + 64 * blockIdx.y;
    const int F = (flat & 7) * 128 + (flat >> 3);
    const int qt = F & 63;   // 32-row q-tile
    const int bh = F >> 6;
    const int b = bh >> 3, h = bh & 7;
    const int q0 = qt * 32 + wave * 16;

    __shared__ __align__(16) u16 kt_lds[2][64 * 64];   // [buf][key-local][dh]
    __shared__ __align__(16) u16 vt_lds[2][64 * 64];   // [buf][dh][key-local]
    __shared__ u16 p_lds[2][16 * 64];    // per-wave P^T as [q][key], XOR-swizzled
    u16* pw = p_lds[wave];

    // Q fragment: lane holds Q[q0+cidx][kg*8+j] (+32). Serves as B-operand of K.Q^T.
    const long qbase = ((long)(b * S_LEN + q0 + cidx)) * DMODEL + h * DHEAD + kg * 8;
    bf16x8 aq0 = ld8(Q + qbase);
    bf16x8 aq1 = ld8(Q + qbase + 32);

    // ones A-fragment: row 0 = 1.0, rows 1..15 = 0. mfma(ones, P^T) row 0 = sum_k P[q][k].
    bf16x8 onesf;
    {
        u16x8 t8;
        u16 ob = (cidx == 0) ? (u16)0x3F80 : (u16)0;
#pragma unroll
        for (int j = 0; j < 8; ++j) t8[j] = ob;
        onesf = *(bf16x8*)&t8;
    }

    const f32x4 fz = {0.f, 0.f, 0.f, 0.f};
    f32x4 acc[4];  // O^T accumulator: lane holds O[q0+cidx][16nt+4kg+r]
#pragma unroll
    for (int nt = 0; nt < 4; ++nt) acc[nt] = fz;
    f32x4 accL = fz;      // after ones-MFMA: lane q (kg==0), comp 0 holds running L[q]
    float mrow = -1e30f;  // per-lane: one q-row (log2 domain, deferred-max reference)

    // staging roles: 128 threads x 4 row-groups of 16. LDS dest LINEAR tid*16B + 1KB*i
    // (gll requirement); global source pre-swizzled seg = kseg ^ (row&7) -> LDS slot s of
    // row r holds global seg s^(r&7), identical content to the swizzled ds_write layout.
    const int krg = tid >> 3, kseg = tid & 7;  // rows {krg, +16, +32, +48}
    const u16* kgbase = K + ((long)(b * S_LEN)) * DMODEL + h * DHEAD;
    const u16* vgbase = Vt + ((long)bh * DHEAD) * S_LEN;
    const u16* kp[4];
    const u16* vp[4];
#pragma unroll
    for (int i = 0; i < 4; ++i) {
        int r = krg + 16 * i;
        int sg = kseg ^ (r & 7);
        kp[i] = kgbase + (long)r * DMODEL + sg * 8;
        vp[i] = vgbase + (long)r * S_LEN + sg * 8;
    }
    const int* flagrow = flags + b * 1024 + (qt >> 1) * 32;
    const int NIT = S_LEN / 64;  // 32 (even -> clean x2 unroll)

    // prologue: tile 0 -> buf0 (async)
#pragma unroll
    for (int i = 0; i < 4; ++i) gll16(kp[i], &kt_lds[0][tid * 8 + 1024 * i]);
#pragma unroll
    for (int i = 0; i < 4; ++i) gll16(vp[i], &vt_lds[0][tid * 8 + 1024 * i]);
    __syncthreads();

#define ATTN_TILE(IT, CUR)                                                                 \
    {                                                                                      \
        if ((IT) + 1 < NIT) {                                                              \
            const int tn = ((IT) + 1) * 64;                                                \
            u16* kn = kt_lds[(CUR) ^ 1];                                                   \
            u16* vn = vt_lds[(CUR) ^ 1];                                                   \
            _Pragma("unroll")                                                              \
            for (int i = 0; i < 4; ++i) gll16(kp[i] + (long)tn * DMODEL, &kn[tid * 8 + 1024 * i]); \
            _Pragma("unroll")                                                              \
            for (int i = 0; i < 4; ++i) gll16(vp[i] + tn, &vn[tid * 8 + 1024 * i]);        \
        }                                                                                  \
        const int flg = flagrow[(IT)];                                                     \
        const u16* kb = kt_lds[(CUR)];                                                     \
        const u16* vb = vt_lds[(CUR)];                                                     \
        f32x4 sacc[4];                                                                     \
        _Pragma("unroll")                                                                  \
        for (int ct = 0; ct < 4; ++ct) sacc[ct] = fz;                                      \
        __builtin_amdgcn_s_setprio(1);                                                     \
        _Pragma("unroll")                                                                  \
        for (int ct = 0; ct < 4; ++ct) {                                                   \
            int r = ct * 16 + cidx;                                                        \
            bf16x8 kv0 = ld8(&kb[r * 64 + ((kg ^ (r & 7)) << 3)]);                         \
            bf16x8 kv1 = ld8(&kb[r * 64 + (((4 ^ kg) ^ (r & 7)) << 3)]);                   \
            sacc[ct] = __builtin_amdgcn_mfma_f32_16x16x32_bf16(kv0, aq0, sacc[ct], 0, 0, 0); \
            sacc[ct] = __builtin_amdgcn_mfma_f32_16x16x32_bf16(kv1, aq1, sacc[ct], 0, 0, 0); \
        }                                                                                  \
        __builtin_amdgcn_s_setprio(0);                                                     \
        if (flg) {                                                                         \
            const float* mb = mask + ((long)(b * S_LEN + q0 + cidx)) * S_LEN + (IT) * 64 + kg * 4; \
            _Pragma("unroll")                                                              \
            for (int ct = 0; ct < 4; ++ct) {                                               \
                f32x4 mv = *(const f32x4*)(mb + ct * 16);                                  \
                _Pragma("unroll")                                                          \
                for (int r = 0; r < 4; ++r) sacc[ct][r] -= MASKC * mv[r];                  \
            }                                                                              \
        }                                                                                  \
        float t0 = fmax3(sacc[0][0], sacc[0][1], sacc[0][2]);                              \
        float t1 = fmax3(sacc[0][3], sacc[1][0], sacc[1][1]);                              \
        float t2 = fmax3(sacc[1][2], sacc[1][3], sacc[2][0]);                              \
        float t3 = fmax3(sacc[2][1], sacc[2][2], sacc[2][3]);                              \
        float t4 = fmax3(sacc[3][0], sacc[3][1], sacc[3][2]);                              \
        float mxl = __builtin_fmaxf(fmax3(fmax3(t0, t1, t2), t3, t4), sacc[3][3]);         \
        if (__any(mxl > mrow + RESCALE_THR)) {                                             \
            float mx = fmaxf(mxl, __shfl_xor(mxl, 16));                                    \
            mx = fmaxf(mx, __shfl_xor(mx, 32));                                            \
            float mnew = fmaxf(mrow, mx);                                                  \
            float alpha = __builtin_amdgcn_exp2f(mrow - mnew);                             \
            mrow = mnew;                                                                   \
            accL = accL * alpha;                                                           \
            _Pragma("unroll")                                                              \
            for (int nt = 0; nt < 4; ++nt) acc[nt] = acc[nt] * alpha;                      \
        }                                                                                  \
        _Pragma("unroll")                                                                  \
        for (int ct = 0; ct < 4; ++ct)                                                     \
            _Pragma("unroll")                                                              \
            for (int r = 0; r < 4; ++r)                                                    \
                sacc[ct][r] = __builtin_amdgcn_exp2f(sacc[ct][r] - mrow);                  \
        _Pragma("unroll")                                                                  \
        for (int ct = 0; ct < 4; ++ct) {                                                   \
            u32x2 d;                                                                       \
            d[0] = pk2bf(sacc[ct][0], sacc[ct][1]);                                        \
            d[1] = pk2bf(sacc[ct][2], sacc[ct][3]);                                        \
            int blk = 2 * ct + (kg >> 1);                                                  \
            *(u32x2*)&pw[cidx * 64 + ((blk ^ (cidx & 7)) << 3) + (kg & 1) * 4] = d;        \
        }                                                                                  \
        bf16x8 pf0 = ld8(&pw[cidx * 64 + ((kg ^ (cidx & 7)) << 3)]);                       \
        bf16x8 pf1 = ld8(&pw[cidx * 64 + (((4 ^ kg) ^ (cidx & 7)) << 3)]);                 \
        __builtin_amdgcn_s_setprio(1);                                                     \
        _Pragma("unroll")                                                                  \
        for (int nt = 0; nt < 4; ++nt) {                                                   \
            int rr = nt * 16 + cidx;                                                       \
            bf16x8 v0 = ld8(&vb[rr * 64 + ((kg ^ (rr & 7)) << 3)]);                        \
            bf16x8 v1 = ld8(&vb[rr * 64 + (((4 ^ kg) ^ (rr & 7)) << 3)]);                  \
            acc[nt] = __builtin_amdgcn_mfma_f32_16x16x32_bf16(v0, pf0, acc[nt], 0, 0, 0);  \
            acc[nt] = __builtin_amdgcn_mfma_f32_16x16x32_bf16(v1, pf1, acc[nt], 0, 0, 0);  \
        }                                                                                  \
        accL = __builtin_amdgcn_mfma_f32_16x16x32_bf16(onesf, pf0, accL, 0, 0, 0);         \
        accL = __builtin_amdgcn_mfma_f32_16x16x32_bf16(onesf, pf1, accL, 0, 0, 0);         \
        __builtin_amdgcn_s_setprio(0);                                                     \
        __syncthreads();  /* drains gll(buf^1); reads of buf[cur] complete */              \
    }

    for (int it = 0; it < NIT; it += 2) {
        ATTN_TILE(it, 0)
        ATTN_TILE(it + 1, 1)
    }
#undef ATTN_TILE

    // epilogue: L[q] sits in lane q (kg==0), comp 0 — broadcast, normalize, write bf16 Ab.
    float Lb = __shfl(accL[0], cidx);
    float invL = 1.f / Lb;
    const long abase = ((long)(b * S_LEN + q0 + cidx)) * DMODEL + h * DHEAD;
#pragma unroll
    for (int nt = 0; nt < 4; ++nt) {
        u32x2 d;
        d[0] = pk2bf(acc[nt][0] * invL, acc[nt][1] * invL);
        d[1] = pk2bf(acc[nt][2] * invL, acc[nt][3] * invL);
        *(u32x2*)(Ab + abase + nt * 16 + kg * 4) = d;
    }
}

extern "C" void kernel_launch(void* const* d_in, const int* in_sizes, int n_in,
                              void* d_out, int out_size, void* d_ws, size_t ws_size,
                              hipStream_t stream) {
    const float* q_in = (const float*)d_in[0];
    const float* k_in = (const float*)d_in[1];
    const float* v_in = (const float*)d_in[2];
    const float* mask = (const float*)d_in[3];
    const float* wq = (const float*)d_in[4];
    const float* bq = (const float*)d_in[5];
    const float* wk = (const float*)d_in[6];
    const float* bk = (const float*)d_in[7];
    const float* wv = (const float*)d_in[8];
    const float* bv = (const float*)d_in[9];
    const float* wo = (const float*)d_in[10];
    const float* bo = (const float*)d_in[11];

    // ws layout (u16 units):
    u16* ws = (u16*)d_ws;
    u16* Qb = ws;                       // 2.1M  projected Q (pre-scaled QSCALE)
    u16* Kb = Qb + 2097152;             // 2.1M
    u16* Vt = Kb + 2097152;             // 2.1M  V transposed (B,H,DH,S) - written by qkv_gemm
    u16* wtall = Vt + 2097152;          // 4 x 262144: [wo, wq, wk, wv]
    u16* Sreg = wtall + 4 * 262144;     // 3 x 2.1M: Aq,Ak,Av  (dead after qkv_gemm)
    u16* Ab = Sreg + 3 * 2097152;       // 2.1M  attention output (merged heads)
    int* mflags = (int*)(Ab + 2097152); // 2048 ints

    prep_kernel<<<6144, 256, 0, stream>>>(q_in, k_in, v_in, wq, wk, wv, wo, mask,
                                          Sreg, wtall, mflags);
    qkv_gemm_kernel<<<dim3(8, 32, 3), 256, 0, stream>>>(Sreg, wtall, bq, bk, bv, Qb, Kb, Vt);
    attn_kernel<<<dim3(64, 16), 128, 0, stream>>>(Qb, Kb, Vt, mask, mflags, Ab);
    out_gemm_kernel<<<dim3(8, 64), 256, 0, stream>>>(Ab, wtall, bo, (float*)d_out);
}

// Round 14
// 171.588 us; speedup vs baseline: 1.0455x; 1.0455x over previous
//
#include <hip/hip_runtime.h>
#include <hip/hip_bf16.h>

typedef unsigned short u16;
typedef unsigned int u32;
typedef __bf16 bf16x8 __attribute__((ext_vector_type(8)));
typedef float f32x4 __attribute__((ext_vector_type(4)));
typedef u16 u16x8 __attribute__((ext_vector_type(8)));
typedef u32 u32x2 __attribute__((ext_vector_type(2)));

#define S_LEN 2048
#define DMODEL 512
#define NHEAD 8
#define DHEAD 64
// log2(e); Q is pre-scaled by 0.125*LOG2E so softmax runs in exp2 domain.
#define QSCALE 0.1803368801111204f
#define MASKC 1.4426950409e9f
#define RESCALE_THR 8.0f

static __device__ __forceinline__ u16 f2bf(float f) {
    union { float f; unsigned u; } cv; cv.f = f;
    unsigned u = cv.u;
    return (u16)((u + 0x7fffu + ((u >> 16) & 1u)) >> 16);  // RNE
}
static __device__ __forceinline__ u32 pk2bf(float a, float b) {
    union { __hip_bfloat162 h; u32 u; } cv;
    float2 f2; f2.x = a; f2.y = b;
    cv.h = __float22bfloat162_rn(f2);
    return cv.u;
}
static __device__ __forceinline__ bf16x8 ld8(const u16* p) {
    return *(const bf16x8*)p;
}
static __device__ __forceinline__ float fmax3(float a, float b, float c) {
    return __builtin_fmaxf(__builtin_fmaxf(a, b), c);  // clang fuses to v_max3_f32
}
// async global->LDS, 16B per lane. LDS dest MUST be wave-uniform base + lane*16 (m104);
// swizzles are applied on the GLOBAL source address instead (m173 pattern).
static __device__ __forceinline__ void gll16(const void* g, void* l) {
    __builtin_amdgcn_global_load_lds(
        (const __attribute__((address_space(1))) void*)g,
        (__attribute__((address_space(3))) void*)l, 16, 0, 0);
}

// ---------------- fused prep: qkv fp32->bf16 cvt | weight transpose->bf16 | mask flags ----
// grid.x partition: [0,3072) cvt, [3072,4096) transpose_w, [4096,6144) mask flags. 256 thr.
__global__ __launch_bounds__(256) void prep_kernel(
    const float* __restrict__ q, const float* __restrict__ k, const float* __restrict__ v,
    const float* __restrict__ w0, const float* __restrict__ w1,
    const float* __restrict__ w2, const float* __restrict__ w3,
    const float* __restrict__ mask,
    u16* __restrict__ Aqkv, u16* __restrict__ wtall, int* __restrict__ flags) {
    const int p = blockIdx.x;
    const int tid = threadIdx.x;
    __shared__ float t[32][33];
    __shared__ int wred[4];
    if (p < 3072) {
        const int z = p >> 10, px = p & 1023;
        const float* in = (z == 0) ? q : (z == 1) ? k : v;
        u16* o = Aqkv + (long)z * 2097152;
        long i = ((long)px * 256 + tid) * 8;
        f32x4 a = *(const f32x4*)(in + i);
        f32x4 b = *(const f32x4*)(in + i + 4);
        u16x8 r;
#pragma unroll
        for (int j = 0; j < 4; ++j) { r[j] = f2bf(a[j]); r[4 + j] = f2bf(b[j]); }
        *(u16x8*)(o + i) = r;
    } else if (p < 4096) {
        // W (512x512 fp32) -> Wt bf16 (N x K). slot order in wtall: [wo, wq, wk, wv]
        const int p2 = p - 3072;
        const int z = p2 >> 8, rem = p2 & 255, by = rem >> 4, bx = rem & 15;
        const float* in = (z == 0) ? w0 : (z == 1) ? w1 : (z == 2) ? w2 : w3;
        u16* o = wtall + (long)(((z + 1) & 3)) * 262144;
        const int tx = tid & 31, ty = tid >> 5;
#pragma unroll
        for (int i = 0; i < 4; ++i)
            t[ty + 8 * i][tx] = in[(by * 32 + ty + 8 * i) * DMODEL + bx * 32 + tx];
        __syncthreads();
#pragma unroll
        for (int i = 0; i < 4; ++i)
            o[(bx * 32 + ty + 8 * i) * DMODEL + by * 32 + tx] = f2bf(t[tx][ty + 8 * i]);
    } else {
        const int bid = p - 4096;  // 2*32*32
        const int b = bid >> 10, qt = (bid >> 5) & 31, kt = bid & 31;
        const int r = tid >> 2, cs = tid & 3;
        const float* mp = mask + ((long)(b * S_LEN + qt * 64 + r)) * S_LEN + kt * 64 + cs * 16;
        int nz = 0;
#pragma unroll
        for (int j = 0; j < 4; ++j) {
            f32x4 a = *(const f32x4*)(mp + j * 4);
            nz |= (a[0] != 0.f) | (a[1] != 0.f) | (a[2] != 0.f) | (a[3] != 0.f);
        }
        unsigned long long ball = __ballot(nz);
        if ((tid & 63) == 0) wred[tid >> 6] = (ball != 0ull) ? 1 : 0;
        __syncthreads();
        if (tid == 0) flags[bid] = wred[0] | wred[1] | wred[2] | wred[3];
    }
}

// ---------------- GEMM epilogue (shared) ----------------
template <bool F32OUT, int TM>
static __device__ __forceinline__ void store_c(f32x4 (&acc)[TM][2],
                                               const float* __restrict__ bias,
                                               void* __restrict__ Cp, float oscale,
                                               bool vtout, int m0, int n0, int cidx, int kg) {
    if (vtout) {
        // V-transposed: row = token (b,s), col = channel (h,d); packed 8B stores.
        const int bb = m0 >> 11;  // batch (tile never crosses the 2048 boundary)
#pragma unroll
        for (int j = 0; j < 2; ++j) {
            int col = n0 + j * 16 + cidx;
            float bv = bias[col];
            u16* vt = (u16*)Cp + (((long)(bb * 8 + (col >> 6))) * 64 + (col & 63)) * S_LEN;
#pragma unroll
            for (int i = 0; i < TM; ++i) {
                int s = (m0 + i * 16 + kg * 4) & (S_LEN - 1);
                u32x2 d;
                d[0] = pk2bf(acc[i][j][0] + bv, acc[i][j][1] + bv);
                d[1] = pk2bf(acc[i][j][2] + bv, acc[i][j][3] + bv);
                *(u32x2*)(vt + s) = d;
            }
        }
        return;
    }
#pragma unroll
    for (int j = 0; j < 2; ++j) {
        int col = n0 + j * 16 + cidx;
        float bv = bias[col];
#pragma unroll
        for (int i = 0; i < TM; ++i) {
#pragma unroll
            for (int r = 0; r < 4; ++r) {
                int row = m0 + i * 16 + kg * 4 + r;
                float val = (acc[i][j][r] + bv) * oscale;
                if (F32OUT) {
                    ((float*)Cp)[(long)row * DMODEL + col] = val;
                } else {
                    ((u16*)Cp)[(long)row * DMODEL + col] = f2bf(val);
                }
            }
        }
    }
}

// ---------------- LDS-staged double-buffered GEMM via global_load_lds ----------------
// C(4096x512) = A(4096x512,bf16) @ Wt^T + bias. Tile BM x 64, BK=32, 256 thr (4 waves 2x2).
// LDS linear [BM][32] (gll requires base+lane*16 dest); bank spread via GLOBAL-source
// XOR swizzle: LDS slot s of row r holds global chunk s ^ ((r>>1)&3); reader fetches
// chunk kg at slot kg ^ ((row>>1)&3) -> 2-way bank aliasing only (free, m136).
// Pipeline: issue gll(buf^1, t+1) -> compute buf (ds_read frags + MFMA) -> ONE barrier
// (its vmcnt drain completes the async loads).
template <int BM, bool F32OUT>
static __device__ __forceinline__ void gemm_lds(const u16* __restrict__ Ag,
                                                const u16* __restrict__ Wg,
                                                const float* __restrict__ bias,
                                                void* __restrict__ Cp, float oscale,
                                                bool vtout, int bx, int by) {
    constexpr int MR = BM / 32;        // M fragments per wave
    constexpr int ACH = BM * 4;        // 16B A-chunks per K-step
    constexpr int TOT = ACH + 256;     // + B-chunks
    constexpr int NCH = TOT / 256;     // 3 for BM=128, 2 for BM=64
    static_assert(TOT % 256 == 0, "chunk count must tile 256 threads");
    __shared__ __align__(16) u16 As[2][BM][32];
    __shared__ __align__(16) u16 Bs[2][64][32];

    const int tid = threadIdx.x;
    const int lane = tid & 63;
    const int wave = tid >> 6;
    const int wr = wave >> 1, wc = wave & 1;
    const int cidx = lane & 15;
    const int kg = lane >> 4;

    const u16* gsrc[NCH];
    u16* ldst[NCH][2];
#pragma unroll
    for (int j = 0; j < NCH; ++j) {
        int c = tid + 256 * j;
        if (c < ACH) {
            int r = c >> 2, s = c & 3;
            int sg = s ^ ((r >> 1) & 3);
            gsrc[j] = Ag + (long)(by * BM + r) * DMODEL + sg * 8;
            ldst[j][0] = &As[0][0][0] + c * 8;
            ldst[j][1] = &As[1][0][0] + c * 8;
        } else {
            int c2 = c - ACH;
            int r = c2 >> 2, s = c2 & 3;
            int sg = s ^ ((r >> 1) & 3);
            gsrc[j] = Wg + (long)(bx * 64 + r) * DMODEL + sg * 8;
            ldst[j][0] = &Bs[0][0][0] + c2 * 8;
            ldst[j][1] = &Bs[1][0][0] + c2 * 8;
        }
    }

    // prologue: tile0 -> LDS[0] (async)
#pragma unroll
    for (int j = 0; j < NCH; ++j) gll16(gsrc[j], ldst[j][0]);
    __syncthreads();

    const f32x4 fz = {0.f, 0.f, 0.f, 0.f};
    f32x4 acc[MR][2];
#pragma unroll
    for (int i = 0; i < MR; ++i)
#pragma unroll
        for (int j = 0; j < 2; ++j) acc[i][j] = fz;

    const int mw = wr * (BM / 2);
    const int nw = wc * 32;

#pragma unroll 2
    for (int t = 0; t < 16; ++t) {
        const int cur = t & 1;
        if (t + 1 < 16) {
#pragma unroll
            for (int j = 0; j < NCH; ++j) gll16(gsrc[j] + (t + 1) * 32, ldst[j][cur ^ 1]);
        }
        bf16x8 a[MR], b[2];
#pragma unroll
        for (int i = 0; i < MR; ++i) {
            int rl = mw + i * 16 + cidx;
            a[i] = ld8(&As[cur][rl][(kg ^ ((rl >> 1) & 3)) * 8]);
        }
#pragma unroll
        for (int j = 0; j < 2; ++j) {
            int rl = nw + j * 16 + cidx;
            b[j] = ld8(&Bs[cur][rl][(kg ^ ((rl >> 1) & 3)) * 8]);
        }
        __builtin_amdgcn_s_setprio(1);
#pragma unroll
        for (int i = 0; i < MR; ++i)
#pragma unroll
            for (int j = 0; j < 2; ++j)
                acc[i][j] = __builtin_amdgcn_mfma_f32_16x16x32_bf16(a[i], b[j], acc[i][j], 0, 0, 0);
        __builtin_amdgcn_s_setprio(0);
        __syncthreads();  // drains gll(buf^1) + completes reads of buf[cur]
    }

    store_c<F32OUT, MR>(acc, bias, Cp, oscale, vtout, by * BM + mw, bx * 64 + nw, cidx, kg);
}

// XCD-aware swizzle (T1): remap so the 8 bx-blocks sharing one A row-panel land on ONE XCD.
// Requires gridY % 8 == 0. Bijective.
static __device__ __forceinline__ void xcd_swizzle(int gridX, int gridY, int& bx, int& by) {
    const int flat = blockIdx.x + gridX * blockIdx.y;
    const int xcd = flat & 7;
    const int j = flat >> 3;
    by = xcd * (gridY >> 3) + j / gridX;
    bx = j % gridX;
}

// qkv: BM=128 -> grid (8,32,3) = 768 blocks = 3/CU, 24KB LDS.
__global__ __launch_bounds__(256) void qkv_gemm_kernel(
    const u16* __restrict__ Aqkv,
    const u16* __restrict__ wtall,
    const float* __restrict__ bq, const float* __restrict__ bk, const float* __restrict__ bv,
    u16* __restrict__ Q, u16* __restrict__ K, u16* __restrict__ Vt) {
    const u16* A = Aqkv + (long)blockIdx.z * 2097152;
    const u16* W = wtall + (long)(blockIdx.z + 1) * 262144;  // [wo, wq, wk, wv]
    const float* b;
    u16* C;
    float sc = 1.f;
    bool vt = false;
    if (blockIdx.z == 0) { b = bq; C = Q; sc = QSCALE; }  // fold 1/sqrt(DH)*log2e into Q
    else if (blockIdx.z == 1) { b = bk; C = K; }
    else { b = bv; C = Vt; vt = true; }
    int bx, by;
    xcd_swizzle(8, 32, bx, by);
    gemm_lds<128, false>(A, W, b, C, sc, vt, bx, by);
}

// out: BM=64 -> grid (8,64) = 512 blocks = 2/CU, 16KB LDS.
__global__ __launch_bounds__(256) void out_gemm_kernel(const u16* __restrict__ A,
                                                       const u16* __restrict__ Wt,
                                                       const float* __restrict__ bias,
                                                       float* __restrict__ C) {
    int bx, by;
    xcd_swizzle(8, 64, bx, by);
    gemm_lds<64, true>(A, Wt, bias, C, 1.f, false, bx, by);
}

// ---------------- flash attention, S^T formulation ----------------
// v9: 128-key buffers — TWO 64-key subtiles computed per barrier period (barrier count
// 32 -> 16; each period has ~2x compute to hide gll latency; gll issue batched 8/thread).
// Per-subtile compute byte-identical to v7 (same tile order -> bitwise-same numerics).
// K stored [128][64] (swizzle on full row idx); V stored [64][128] as two side-by-side
// 64-key panels, each with the per-panel swizzle. LDS 72KB -> still 2 blocks/CU.
__global__ __launch_bounds__(256) void attn_kernel(const u16* __restrict__ Q,
                                                   const u16* __restrict__ K,
                                                   const u16* __restrict__ Vt,
                                                   const float* __restrict__ mask,
                                                   const int* __restrict__ flags,
                                                   u16* __restrict__ Ab) {
    const int tid = threadIdx.x;
    const int lane = tid & 63;
    const int wave = tid >> 6;
    const int cidx = lane & 15;   // q-row (QK^T B-operand col / PV B-col); d-row for V A-frag
    const int kg = lane >> 4;
    // XCD-aware remap: XCD j gets F in [64j, 64j+64) = all 32 q-tiles of bh pair {2j, 2j+1}.
    const int flat = blockIdx.x + 32 * blockIdx.y;
    const int F = (flat & 7) * 64 + (flat >> 3);
    const int qt = F & 31;
    const int bh = F >> 5;
    const int b = bh >> 3, h = bh & 7;
    const int q0 = qt * 64 + wave * 16;

    __shared__ __align__(16) u16 kt_lds[2][128 * 64];  // [buf][key-local][dh]
    __shared__ __align__(16) u16 vt_lds[2][64 * 128];  // [buf][dh][2 x 64-key panels]
    __shared__ u16 p_lds[4][16 * 64];    // per-wave P^T as [q][key], XOR-swizzled
    u16* pw = p_lds[wave];

    // Q fragment: lane holds Q[q0+cidx][kg*8+j] (+32). Serves as B-operand of K.Q^T.
    const long qbase = ((long)(b * S_LEN + q0 + cidx)) * DMODEL + h * DHEAD + kg * 8;
    bf16x8 aq0 = ld8(Q + qbase);
    bf16x8 aq1 = ld8(Q + qbase + 32);

    // ones A-fragment: row 0 = 1.0, rows 1..15 = 0. mfma(ones, P^T) row 0 = sum_k P[q][k].
    bf16x8 onesf;
    {
        u16x8 t8;
        u16 ob = (cidx == 0) ? (u16)0x3F80 : (u16)0;
#pragma unroll
        for (int j = 0; j < 8; ++j) t8[j] = ob;
        onesf = *(bf16x8*)&t8;
    }

    const f32x4 fz = {0.f, 0.f, 0.f, 0.f};
    f32x4 acc[4];  // O^T accumulator: lane holds O[q0+cidx][16nt+4kg+r]
#pragma unroll
    for (int nt = 0; nt < 4; ++nt) acc[nt] = fz;
    f32x4 accL = fz;      // after ones-MFMA: lane q (kg==0), comp 0 holds running L[q]
    float mrow = -1e30f;  // per-lane: one q-row (log2 domain, deferred-max reference)

    // staging: LDS dest fixed linear (chunk c = tid+256j at u16 offset c*8); the global
    // source supplies the element that belongs there (seg pre-XORed with the row).
    // K [128][64]: c -> row kr=c>>3 (0..127), slot sl=c&7 -> src seg sl^(kr&7).
    // V [64][128]: c -> row vr=c>>4 (0..63), half hh=(c>>3)&1, slot sl -> seg sl^(vr&7).
    const u16* kgbase = K + ((long)(b * S_LEN)) * DMODEL + h * DHEAD;
    const u16* vgbase = Vt + ((long)bh * DHEAD) * S_LEN;
    const u16* kpp[4];
    const u16* vpp[4];
    {
        const int sl = tid & 7;
#pragma unroll
        for (int j = 0; j < 4; ++j) {
            int kr = (tid >> 3) + 32 * j;
            kpp[j] = kgbase + (long)kr * DMODEL + (sl ^ (kr & 7)) * 8;
            int vr = (tid >> 4) + 16 * j;
            int hh = (tid >> 3) & 1;
            vpp[j] = vgbase + (long)vr * S_LEN + hh * 64 + (sl ^ (vr & 7)) * 8;
        }
    }
    const int* flagrow = flags + b * 1024 + qt * 32;
    const int NI2 = S_LEN / 128;  // 16 iterations of 128 keys

#define STAGE_ITER(IT, BUF)                                                                \
    {                                                                                      \
        u16* kn = kt_lds[(BUF)];                                                           \
        u16* vn = vt_lds[(BUF)];                                                           \
        const long ko = (long)((IT) * 128) * DMODEL;                                       \
        const int vo = (IT) * 128;                                                         \
        _Pragma("unroll")                                                                  \
        for (int j = 0; j < 4; ++j) gll16(kpp[j] + ko, &kn[(tid + 256 * j) * 8]);          \
        _Pragma("unroll")                                                                  \
        for (int j = 0; j < 4; ++j) gll16(vpp[j] + vo, &vn[(tid + 256 * j) * 8]);          \
    }

#define ATTN_SUB(IT, CUR, H)                                                               \
    {                                                                                      \
        const int flg = flagrow[(IT) * 2 + (H)];                                           \
        const u16* kb = kt_lds[(CUR)];                                                     \
        const u16* vb = vt_lds[(CUR)];                                                     \
        f32x4 sacc[4];                                                                     \
        _Pragma("unroll")                                                                  \
        for (int ct = 0; ct < 4; ++ct) sacc[ct] = fz;                                      \
        __builtin_amdgcn_s_setprio(1);                                                     \
        _Pragma("unroll")                                                                  \
        for (int ct = 0; ct < 4; ++ct) {                                                   \
            int r = (H) * 64 + ct * 16 + cidx;                                             \
            bf16x8 kv0 = ld8(&kb[r * 64 + ((kg ^ (r & 7)) << 3)]);                         \
            bf16x8 kv1 = ld8(&kb[r * 64 + (((4 ^ kg) ^ (r & 7)) << 3)]);                   \
            sacc[ct] = __builtin_amdgcn_mfma_f32_16x16x32_bf16(kv0, aq0, sacc[ct], 0, 0, 0); \
            sacc[ct] = __builtin_amdgcn_mfma_f32_16x16x32_bf16(kv1, aq1, sacc[ct], 0, 0, 0); \
        }                                                                                  \
        __builtin_amdgcn_s_setprio(0);                                                     \
        if (flg) {                                                                         \
            const float* mb = mask + ((long)(b * S_LEN + q0 + cidx)) * S_LEN               \
                              + (IT) * 128 + (H) * 64 + kg * 4;                            \
            _Pragma("unroll")                                                              \
            for (int ct = 0; ct < 4; ++ct) {                                               \
                f32x4 mv = *(const f32x4*)(mb + ct * 16);                                  \
                _Pragma("unroll")                                                          \
                for (int r = 0; r < 4; ++r) sacc[ct][r] -= MASKC * mv[r];                  \
            }                                                                              \
        }                                                                                  \
        float t0 = fmax3(sacc[0][0], sacc[0][1], sacc[0][2]);                              \
        float t1 = fmax3(sacc[0][3], sacc[1][0], sacc[1][1]);                              \
        float t2 = fmax3(sacc[1][2], sacc[1][3], sacc[2][0]);                              \
        float t3 = fmax3(sacc[2][1], sacc[2][2], sacc[2][3]);                              \
        float t4 = fmax3(sacc[3][0], sacc[3][1], sacc[3][2]);                              \
        float mxl = __builtin_fmaxf(fmax3(fmax3(t0, t1, t2), t3, t4), sacc[3][3]);         \
        if (__any(mxl > mrow + RESCALE_THR)) {                                             \
            float mx = fmaxf(mxl, __shfl_xor(mxl, 16));                                    \
            mx = fmaxf(mx, __shfl_xor(mx, 32));                                            \
            float mnew = fmaxf(mrow, mx);                                                  \
            float alpha = __builtin_amdgcn_exp2f(mrow - mnew);                             \
            mrow = mnew;                                                                   \
            accL = accL * alpha;                                                           \
            _Pragma("unroll")                                                              \
            for (int nt = 0; nt < 4; ++nt) acc[nt] = acc[nt] * alpha;                      \
        }                                                                                  \
        _Pragma("unroll")                                                                  \
        for (int ct = 0; ct < 4; ++ct)                                                     \
            _Pragma("unroll")                                                              \
            for (int r = 0; r < 4; ++r)                                                    \
                sacc[ct][r] = __builtin_amdgcn_exp2f(sacc[ct][r] - mrow);                  \
        _Pragma("unroll")                                                                  \
        for (int ct = 0; ct < 4; ++ct) {                                                   \
            u32x2 d;                                                                       \
            d[0] = pk2bf(sacc[ct][0], sacc[ct][1]);                                        \
            d[1] = pk2bf(sacc[ct][2], sacc[ct][3]);                                        \
            int blk = 2 * ct + (kg >> 1);                                                  \
            *(u32x2*)&pw[cidx * 64 + ((blk ^ (cidx & 7)) << 3) + (kg & 1) * 4] = d;        \
        }                                                                                  \
        bf16x8 pf0 = ld8(&pw[cidx * 64 + ((kg ^ (cidx & 7)) << 3)]);                       \
        bf16x8 pf1 = ld8(&pw[cidx * 64 + (((4 ^ kg) ^ (cidx & 7)) << 3)]);                 \
        __builtin_amdgcn_s_setprio(1);                                                     \
        _Pragma("unroll")                                                                  \
        for (int nt = 0; nt < 4; ++nt) {                                                   \
            int rr = nt * 16 + cidx;                                                       \
            bf16x8 v0 = ld8(&vb[rr * 128 + (H) * 64 + ((kg ^ (rr & 7)) << 3)]);            \
            bf16x8 v1 = ld8(&vb[rr * 128 + (H) * 64 + (((4 ^ kg) ^ (rr & 7)) << 3)]);      \
            acc[nt] = __builtin_amdgcn_mfma_f32_16x16x32_bf16(v0, pf0, acc[nt], 0, 0, 0);  \
            acc[nt] = __builtin_amdgcn_mfma_f32_16x16x32_bf16(v1, pf1, acc[nt], 0, 0, 0);  \
        }                                                                                  \
        accL = __builtin_amdgcn_mfma_f32_16x16x32_bf16(onesf, pf0, accL, 0, 0, 0);         \
        accL = __builtin_amdgcn_mfma_f32_16x16x32_bf16(onesf, pf1, accL, 0, 0, 0);         \
        __builtin_amdgcn_s_setprio(0);                                                     \
    }

    // prologue: iter 0 -> buf0 (async)
    STAGE_ITER(0, 0)
    __syncthreads();

    for (int it = 0; it < NI2; it += 2) {
        if (it + 1 < NI2) STAGE_ITER(it + 1, 1)
        ATTN_SUB(it, 0, 0)
        ATTN_SUB(it, 0, 1)
        __syncthreads();
        if (it + 2 < NI2) STAGE_ITER(it + 2, 0)
        ATTN_SUB(it + 1, 1, 0)
        ATTN_SUB(it + 1, 1, 1)
        __syncthreads();
    }
#undef ATTN_SUB
#undef STAGE_ITER

    // epilogue: L[q] sits in lane q (kg==0), comp 0 — broadcast, normalize, write bf16 Ab.
    float Lb = __shfl(accL[0], cidx);
    float invL = 1.f / Lb;
    const long abase = ((long)(b * S_LEN + q0 + cidx)) * DMODEL + h * DHEAD;
#pragma unroll
    for (int nt = 0; nt < 4; ++nt) {
        u32x2 d;
        d[0] = pk2bf(acc[nt][0] * invL, acc[nt][1] * invL);
        d[1] = pk2bf(acc[nt][2] * invL, acc[nt][3] * invL);
        *(u32x2*)(Ab + abase + nt * 16 + kg * 4) = d;
    }
}

extern "C" void kernel_launch(void* const* d_in, const int* in_sizes, int n_in,
                              void* d_out, int out_size, void* d_ws, size_t ws_size,
                              hipStream_t stream) {
    const float* q_in = (const float*)d_in[0];
    const float* k_in = (const float*)d_in[1];
    const float* v_in = (const float*)d_in[2];
    const float* mask = (const float*)d_in[3];
    const float* wq = (const float*)d_in[4];
    const float* bq = (const float*)d_in[5];
    const float* wk = (const float*)d_in[6];
    const float* bk = (const float*)d_in[7];
    const float* wv = (const float*)d_in[8];
    const float* bv = (const float*)d_in[9];
    const float* wo = (const float*)d_in[10];
    const float* bo = (const float*)d_in[11];

    // ws layout (u16 units):
    u16* ws = (u16*)d_ws;
    u16* Qb = ws;                       // 2.1M  projected Q (pre-scaled QSCALE)
    u16* Kb = Qb + 2097152;             // 2.1M
    u16* Vt = Kb + 2097152;             // 2.1M  V transposed (B,H,DH,S) - written by qkv_gemm
    u16* wtall = Vt + 2097152;          // 4 x 262144: [wo, wq, wk, wv]
    u16* Sreg = wtall + 4 * 262144;     // 3 x 2.1M: Aq,Ak,Av  (dead after qkv_gemm)
    u16* Ab = Sreg + 3 * 2097152;       // 2.1M  attention output (merged heads)
    int* mflags = (int*)(Ab + 2097152); // 2048 ints

    prep_kernel<<<6144, 256, 0, stream>>>(q_in, k_in, v_in, wq, wk, wv, wo, mask,
                                          Sreg, wtall, mflags);
    qkv_gemm_kernel<<<dim3(8, 32, 3), 256, 0, stream>>>(Sreg, wtall, bq, bk, bv, Qb, Kb, Vt);
    attn_kernel<<<dim3(32, 16), 256, 0, stream>>>(Qb, Kb, Vt, mask, mflags, Ab);
    out_gemm_kernel<<<dim3(8, 64), 256, 0, stream>>>(Ab, wtall, bo, (float*)d_out);
}

// Round 15
// 170.162 us; speedup vs baseline: 1.0543x; 1.0084x over previous
//
#include <hip/hip_runtime.h>
#include <hip/hip_bf16.h>

typedef unsigned short u16;
typedef unsigned int u32;
typedef __bf16 bf16x8 __attribute__((ext_vector_type(8)));
typedef float f32x4 __attribute__((ext_vector_type(4)));
typedef u16 u16x8 __attribute__((ext_vector_type(8)));
typedef u32 u32x2 __attribute__((ext_vector_type(2)));

#define S_LEN 2048
#define DMODEL 512
#define NHEAD 8
#define DHEAD 64
// log2(e); Q is pre-scaled by 0.125*LOG2E so softmax runs in exp2 domain.
#define QSCALE 0.1803368801111204f
#define MASKC 1.4426950409e9f
#define RESCALE_THR 8.0f

static __device__ __forceinline__ u16 f2bf(float f) {
    union { float f; unsigned u; } cv; cv.f = f;
    unsigned u = cv.u;
    return (u16)((u + 0x7fffu + ((u >> 16) & 1u)) >> 16);  // RNE
}
static __device__ __forceinline__ u32 pk2bf(float a, float b) {
    union { __hip_bfloat162 h; u32 u; } cv;
    float2 f2; f2.x = a; f2.y = b;
    cv.h = __float22bfloat162_rn(f2);
    return cv.u;
}
static __device__ __forceinline__ bf16x8 ld8(const u16* p) {
    return *(const bf16x8*)p;
}
static __device__ __forceinline__ float fmax3(float a, float b, float c) {
    return __builtin_fmaxf(__builtin_fmaxf(a, b), c);  // clang fuses to v_max3_f32
}
// async global->LDS, 16B per lane. LDS dest MUST be wave-uniform base + lane*16 (m104);
// swizzles are applied on the GLOBAL source address instead (m173 pattern).
static __device__ __forceinline__ void gll16(const void* g, void* l) {
    __builtin_amdgcn_global_load_lds(
        (const __attribute__((address_space(1))) void*)g,
        (__attribute__((address_space(3))) void*)l, 16, 0, 0);
}

// ---------------- fused prep: qkv fp32->bf16 cvt | weight transpose->bf16 | mask flags ----
// grid.x partition: [0,3072) cvt, [3072,4096) transpose_w, [4096,6144) mask flags. 256 thr.
__global__ __launch_bounds__(256) void prep_kernel(
    const float* __restrict__ q, const float* __restrict__ k, const float* __restrict__ v,
    const float* __restrict__ w0, const float* __restrict__ w1,
    const float* __restrict__ w2, const float* __restrict__ w3,
    const float* __restrict__ mask,
    u16* __restrict__ Aqkv, u16* __restrict__ wtall, int* __restrict__ flags) {
    const int p = blockIdx.x;
    const int tid = threadIdx.x;
    __shared__ float t[32][33];
    __shared__ int wred[4];
    if (p < 3072) {
        const int z = p >> 10, px = p & 1023;
        const float* in = (z == 0) ? q : (z == 1) ? k : v;
        u16* o = Aqkv + (long)z * 2097152;
        long i = ((long)px * 256 + tid) * 8;
        f32x4 a = *(const f32x4*)(in + i);
        f32x4 b = *(const f32x4*)(in + i + 4);
        u16x8 r;
#pragma unroll
        for (int j = 0; j < 4; ++j) { r[j] = f2bf(a[j]); r[4 + j] = f2bf(b[j]); }
        *(u16x8*)(o + i) = r;
    } else if (p < 4096) {
        // W (512x512 fp32) -> Wt bf16 (N x K). slot order in wtall: [wo, wq, wk, wv]
        const int p2 = p - 3072;
        const int z = p2 >> 8, rem = p2 & 255, by = rem >> 4, bx = rem & 15;
        const float* in = (z == 0) ? w0 : (z == 1) ? w1 : (z == 2) ? w2 : w3;
        u16* o = wtall + (long)(((z + 1) & 3)) * 262144;
        const int tx = tid & 31, ty = tid >> 5;
#pragma unroll
        for (int i = 0; i < 4; ++i)
            t[ty + 8 * i][tx] = in[(by * 32 + ty + 8 * i) * DMODEL + bx * 32 + tx];
        __syncthreads();
#pragma unroll
        for (int i = 0; i < 4; ++i)
            o[(bx * 32 + ty + 8 * i) * DMODEL + by * 32 + tx] = f2bf(t[tx][ty + 8 * i]);
    } else {
        const int bid = p - 4096;  // 2*32*32
        const int b = bid >> 10, qt = (bid >> 5) & 31, kt = bid & 31;
        const int r = tid >> 2, cs = tid & 3;
        const float* mp = mask + ((long)(b * S_LEN + qt * 64 + r)) * S_LEN + kt * 64 + cs * 16;
        int nz = 0;
#pragma unroll
        for (int j = 0; j < 4; ++j) {
            f32x4 a = *(const f32x4*)(mp + j * 4);
            nz |= (a[0] != 0.f) | (a[1] != 0.f) | (a[2] != 0.f) | (a[3] != 0.f);
        }
        unsigned long long ball = __ballot(nz);
        if ((tid & 63) == 0) wred[tid >> 6] = (ball != 0ull) ? 1 : 0;
        __syncthreads();
        if (tid == 0) flags[bid] = wred[0] | wred[1] | wred[2] | wred[3];
    }
}

// ---------------- GEMM epilogue (shared) ----------------
template <bool F32OUT, int TM>
static __device__ __forceinline__ void store_c(f32x4 (&acc)[TM][2],
                                               const float* __restrict__ bias,
                                               void* __restrict__ Cp, float oscale,
                                               bool vtout, int m0, int n0, int cidx, int kg) {
    if (vtout) {
        // V-transposed: row = token (b,s), col = channel (h,d); packed 8B stores.
        const int bb = m0 >> 11;  // batch (tile never crosses the 2048 boundary)
#pragma unroll
        for (int j = 0; j < 2; ++j) {
            int col = n0 + j * 16 + cidx;
            float bv = bias[col];
            u16* vt = (u16*)Cp + (((long)(bb * 8 + (col >> 6))) * 64 + (col & 63)) * S_LEN;
#pragma unroll
            for (int i = 0; i < TM; ++i) {
                int s = (m0 + i * 16 + kg * 4) & (S_LEN - 1);
                u32x2 d;
                d[0] = pk2bf(acc[i][j][0] + bv, acc[i][j][1] + bv);
                d[1] = pk2bf(acc[i][j][2] + bv, acc[i][j][3] + bv);
                *(u32x2*)(vt + s) = d;
            }
        }
        return;
    }
#pragma unroll
    for (int j = 0; j < 2; ++j) {
        int col = n0 + j * 16 + cidx;
        float bv = bias[col];
#pragma unroll
        for (int i = 0; i < TM; ++i) {
#pragma unroll
            for (int r = 0; r < 4; ++r) {
                int row = m0 + i * 16 + kg * 4 + r;
                float val = (acc[i][j][r] + bv) * oscale;
                if (F32OUT) {
                    ((float*)Cp)[(long)row * DMODEL + col] = val;
                } else {
                    ((u16*)Cp)[(long)row * DMODEL + col] = f2bf(val);
                }
            }
        }
    }
}

// ---------------- LDS-staged double-buffered GEMM via global_load_lds ----------------
// C(4096x512) = A(4096x512,bf16) @ Wt^T + bias. Tile BM x 64, BK=32, 256 thr (4 waves).
// BM>=64: waves 2x2 (wave tile (BM/2)x32); BM=32: waves 1x4... kept 2x2 with MR=1 and
// wave-rows overlapping is wrong -> for BM=32 use wave tile 16x32 via wr=wave>>1 (2 rows
// of waves over 32 rows). LDS linear (gll dest); bank spread via GLOBAL-source XOR:
// LDS slot s of row r holds global chunk s ^ ((r>>1)&3); reader XORs the same.
// Pipeline: issue gll(buf^1, t+1) -> compute buf -> ONE barrier (vmcnt drain).
template <int BM, bool F32OUT>
static __device__ __forceinline__ void gemm_lds(const u16* __restrict__ Ag,
                                                const u16* __restrict__ Wg,
                                                const float* __restrict__ bias,
                                                void* __restrict__ Cp, float oscale,
                                                bool vtout, int bx, int by) {
    constexpr int MR = BM / 32;             // M fragments per wave (>=1)
    constexpr int ACH = BM * 4;             // 16B A-chunks per K-step
    constexpr int TOT = ACH + 256;          // + B-chunks
    constexpr int NCH = (TOT + 255) / 256;  // guarded when TOT%256 != 0
    __shared__ __align__(16) u16 As[2][BM][32];
    __shared__ __align__(16) u16 Bs[2][64][32];

    const int tid = threadIdx.x;
    const int lane = tid & 63;
    const int wave = tid >> 6;
    const int wr = wave >> 1, wc = wave & 1;
    const int cidx = lane & 15;
    const int kg = lane >> 4;

    const u16* gsrc[NCH];
    u16* ldst[NCH][2];
    bool val[NCH];
#pragma unroll
    for (int j = 0; j < NCH; ++j) {
        int c = tid + 256 * j;
        val[j] = (c < TOT);
        int cc = val[j] ? c : 0;
        if (cc < ACH) {
            int r = cc >> 2, s = cc & 3;
            int sg = s ^ ((r >> 1) & 3);
            gsrc[j] = Ag + (long)(by * BM + r) * DMODEL + sg * 8;
            ldst[j][0] = &As[0][0][0] + cc * 8;
            ldst[j][1] = &As[1][0][0] + cc * 8;
        } else {
            int c2 = cc - ACH;
            int r = c2 >> 2, s = c2 & 3;
            int sg = s ^ ((r >> 1) & 3);
            gsrc[j] = Wg + (long)(bx * 64 + r) * DMODEL + sg * 8;
            ldst[j][0] = &Bs[0][0][0] + c2 * 8;
            ldst[j][1] = &Bs[1][0][0] + c2 * 8;
        }
    }

    // prologue: tile0 -> LDS[0] (async)
#pragma unroll
    for (int j = 0; j < NCH; ++j) if (val[j]) gll16(gsrc[j], ldst[j][0]);
    __syncthreads();

    const f32x4 fz = {0.f, 0.f, 0.f, 0.f};
    f32x4 acc[MR][2];
#pragma unroll
    for (int i = 0; i < MR; ++i)
#pragma unroll
        for (int j = 0; j < 2; ++j) acc[i][j] = fz;

    // wave tiling: BM>=64 -> 2x2 waves, wave rows = BM/2; BM=32 -> wr in {0,1} maps to
    // 16-row halves (MR=1): mw = wr*16.
    const int mw = (BM >= 64) ? wr * (BM / 2) : wr * 16;
    const int nw = wc * 32;

#pragma unroll 2
    for (int t = 0; t < 16; ++t) {
        const int cur = t & 1;
        if (t + 1 < 16) {
#pragma unroll
            for (int j = 0; j < NCH; ++j)
                if (val[j]) gll16(gsrc[j] + (t + 1) * 32, ldst[j][cur ^ 1]);
        }
        bf16x8 a[MR], b[2];
#pragma unroll
        for (int i = 0; i < MR; ++i) {
            int rl = mw + i * 16 + cidx;
            a[i] = ld8(&As[cur][rl][(kg ^ ((rl >> 1) & 3)) * 8]);
        }
#pragma unroll
        for (int j = 0; j < 2; ++j) {
            int rl = nw + j * 16 + cidx;
            b[j] = ld8(&Bs[cur][rl][(kg ^ ((rl >> 1) & 3)) * 8]);
        }
        __builtin_amdgcn_s_setprio(1);
#pragma unroll
        for (int i = 0; i < MR; ++i)
#pragma unroll
            for (int j = 0; j < 2; ++j)
                acc[i][j] = __builtin_amdgcn_mfma_f32_16x16x32_bf16(a[i], b[j], acc[i][j], 0, 0, 0);
        __builtin_amdgcn_s_setprio(0);
        __syncthreads();  // drains gll(buf^1) + completes reads of buf[cur]
    }

    store_c<F32OUT, MR>(acc, bias, Cp, oscale, vtout, by * BM + mw, bx * 64 + nw, cidx, kg);
}

// XCD-aware swizzle (T1): remap so the 8 bx-blocks sharing one A row-panel land on ONE XCD.
// Requires gridY % 8 == 0. Bijective.
static __device__ __forceinline__ void xcd_swizzle(int gridX, int gridY, int& bx, int& by) {
    const int flat = blockIdx.x + gridX * blockIdx.y;
    const int xcd = flat & 7;
    const int j = flat >> 3;
    by = xcd * (gridY >> 3) + j / gridX;
    bx = j % gridX;
}

// qkv: BM=128 -> grid (8,32,3) = 768 blocks = 3/CU, 24KB LDS.
__global__ __launch_bounds__(256) void qkv_gemm_kernel(
    const u16* __restrict__ Aqkv,
    const u16* __restrict__ wtall,
    const float* __restrict__ bq, const float* __restrict__ bk, const float* __restrict__ bv,
    u16* __restrict__ Q, u16* __restrict__ K, u16* __restrict__ Vt) {
    const u16* A = Aqkv + (long)blockIdx.z * 2097152;
    const u16* W = wtall + (long)(blockIdx.z + 1) * 262144;  // [wo, wq, wk, wv]
    const float* b;
    u16* C;
    float sc = 1.f;
    bool vt = false;
    if (blockIdx.z == 0) { b = bq; C = Q; sc = QSCALE; }  // fold 1/sqrt(DH)*log2e into Q
    else if (blockIdx.z == 1) { b = bk; C = K; }
    else { b = bv; C = Vt; vt = true; }
    int bx, by;
    xcd_swizzle(8, 32, bx, by);
    gemm_lds<128, false>(A, W, b, C, sc, vt, bx, by);
}

// out: BM=32 -> grid (8,128) = 1024 blocks = 4/CU (2x residency vs BM=64), 12KB LDS.
__global__ __launch_bounds__(256) void out_gemm_kernel(const u16* __restrict__ A,
                                                       const u16* __restrict__ Wt,
                                                       const float* __restrict__ bias,
                                                       float* __restrict__ C) {
    int bx, by;
    xcd_swizzle(8, 128, bx, by);
    gemm_lds<32, true>(A, Wt, bias, C, 1.f, false, bx, by);
}

// ---------------- flash attention, S^T formulation (R12-exact: best gll variant) ----------
__global__ __launch_bounds__(256) void attn_kernel(const u16* __restrict__ Q,
                                                   const u16* __restrict__ K,
                                                   const u16* __restrict__ Vt,
                                                   const float* __restrict__ mask,
                                                   const int* __restrict__ flags,
                                                   u16* __restrict__ Ab) {
    const int tid = threadIdx.x;
    const int lane = tid & 63;
    const int wave = tid >> 6;
    const int cidx = lane & 15;   // q-row (QK^T B-operand col / PV B-col); d-row for V A-frag
    const int kg = lane >> 4;
    // XCD-aware remap: XCD j gets F in [64j, 64j+64) = all 32 q-tiles of bh pair {2j, 2j+1}.
    const int flat = blockIdx.x + 32 * blockIdx.y;
    const int F = (flat & 7) * 64 + (flat >> 3);
    const int qt = F & 31;
    const int bh = F >> 5;
    const int b = bh >> 3, h = bh & 7;
    const int q0 = qt * 64 + wave * 16;

    __shared__ __align__(16) u16 kt_lds[2][64 * 64];   // [buf][key-local][dh]
    __shared__ __align__(16) u16 vt_lds[2][64 * 64];   // [buf][dh][key-local]
    __shared__ u16 p_lds[4][16 * 64];    // per-wave P^T as [q][key], XOR-swizzled
    u16* pw = p_lds[wave];

    // Q fragment: lane holds Q[q0+cidx][kg*8+j] (+32). Serves as B-operand of K.Q^T.
    const long qbase = ((long)(b * S_LEN + q0 + cidx)) * DMODEL + h * DHEAD + kg * 8;
    bf16x8 aq0 = ld8(Q + qbase);
    bf16x8 aq1 = ld8(Q + qbase + 32);

    // ones A-fragment: row 0 = 1.0, rows 1..15 = 0. mfma(ones, P^T) row 0 = sum_k P[q][k].
    bf16x8 onesf;
    {
        u16x8 t8;
        u16 ob = (cidx == 0) ? (u16)0x3F80 : (u16)0;
#pragma unroll
        for (int j = 0; j < 8; ++j) t8[j] = ob;
        onesf = *(bf16x8*)&t8;
    }

    const f32x4 fz = {0.f, 0.f, 0.f, 0.f};
    f32x4 acc[4];  // O^T accumulator: lane holds O[q0+cidx][16nt+4kg+r]
#pragma unroll
    for (int nt = 0; nt < 4; ++nt) acc[nt] = fz;
    f32x4 accL = fz;      // after ones-MFMA: lane q (kg==0), comp 0 holds running L[q]
    float mrow = -1e30f;  // per-lane: one q-row (log2 domain, deferred-max reference)

    // staging roles: lane slot (krow=tid>>3, kseg=tid&7); LDS dest is LINEAR tid*16B per
    // 32-row half; global source pre-swizzled seg = kseg ^ (krow&7) -> LDS slot s holds
    // global seg s^(krow&7), identical content to the swizzled ds_write layout.
    const int krow0 = tid >> 3, kseg0 = tid & 7;  // rows 0..31
    const int krow1 = krow0 + 32;                 // rows 32..63
    const u16* kgbase = K + ((long)(b * S_LEN)) * DMODEL + h * DHEAD;
    const u16* vgbase = Vt + ((long)bh * DHEAD) * S_LEN;
    const int sg0 = kseg0 ^ (krow0 & 7);
    const int sg1 = kseg0 ^ (krow1 & 7);
    const int* flagrow = flags + b * 1024 + qt * 32;
    const int NIT = S_LEN / 64;  // 32 (even -> clean x2 unroll)

    const u16* kp0 = kgbase + (long)krow0 * DMODEL + sg0 * 8;
    const u16* kp1 = kgbase + (long)krow1 * DMODEL + sg1 * 8;
    const u16* vp0 = vgbase + (long)krow0 * S_LEN + sg0 * 8;
    const u16* vp1 = vgbase + (long)krow1 * S_LEN + sg1 * 8;

    // prologue: tile 0 -> buf0 (async)
    gll16(kp0, &kt_lds[0][tid * 8]);
    gll16(kp1, &kt_lds[0][2048 + tid * 8]);
    gll16(vp0, &vt_lds[0][tid * 8]);
    gll16(vp1, &vt_lds[0][2048 + tid * 8]);
    __syncthreads();

#define ATTN_TILE(IT, CUR)                                                                 \
    {                                                                                      \
        if ((IT) + 1 < NIT) {                                                              \
            const int tn = ((IT) + 1) * 64;                                                \
            u16* kn = kt_lds[(CUR) ^ 1];                                                   \
            u16* vn = vt_lds[(CUR) ^ 1];                                                   \
            gll16(kp0 + (long)tn * DMODEL, &kn[tid * 8]);                                  \
            gll16(kp1 + (long)tn * DMODEL, &kn[2048 + tid * 8]);                           \
            gll16(vp0 + tn, &vn[tid * 8]);                                                 \
            gll16(vp1 + tn, &vn[2048 + tid * 8]);                                          \
        }                                                                                  \
        const int flg = flagrow[(IT)];                                                     \
        const u16* kb = kt_lds[(CUR)];                                                     \
        const u16* vb = vt_lds[(CUR)];                                                     \
        f32x4 sacc[4];                                                                     \
        _Pragma("unroll")                                                                  \
        for (int ct = 0; ct < 4; ++ct) sacc[ct] = fz;                                      \
        __builtin_amdgcn_s_setprio(1);                                                     \
        _Pragma("unroll")                                                                  \
        for (int ct = 0; ct < 4; ++ct) {                                                   \
            int r = ct * 16 + cidx;                                                        \
            bf16x8 kv0 = ld8(&kb[r * 64 + ((kg ^ (r & 7)) << 3)]);                         \
            bf16x8 kv1 = ld8(&kb[r * 64 + (((4 ^ kg) ^ (r & 7)) << 3)]);                   \
            sacc[ct] = __builtin_amdgcn_mfma_f32_16x16x32_bf16(kv0, aq0, sacc[ct], 0, 0, 0); \
            sacc[ct] = __builtin_amdgcn_mfma_f32_16x16x32_bf16(kv1, aq1, sacc[ct], 0, 0, 0); \
        }                                                                                  \
        __builtin_amdgcn_s_setprio(0);                                                     \
        if (flg) {                                                                         \
            const float* mb = mask + ((long)(b * S_LEN + q0 + cidx)) * S_LEN + (IT) * 64 + kg * 4; \
            _Pragma("unroll")                                                              \
            for (int ct = 0; ct < 4; ++ct) {                                               \
                f32x4 mv = *(const f32x4*)(mb + ct * 16);                                  \
                _Pragma("unroll")                                                          \
                for (int r = 0; r < 4; ++r) sacc[ct][r] -= MASKC * mv[r];                  \
            }                                                                              \
        }                                                                                  \
        float t0 = fmax3(sacc[0][0], sacc[0][1], sacc[0][2]);                              \
        float t1 = fmax3(sacc[0][3], sacc[1][0], sacc[1][1]);                              \
        float t2 = fmax3(sacc[1][2], sacc[1][3], sacc[2][0]);                              \
        float t3 = fmax3(sacc[2][1], sacc[2][2], sacc[2][3]);                              \
        float t4 = fmax3(sacc[3][0], sacc[3][1], sacc[3][2]);                              \
        float mxl = __builtin_fmaxf(fmax3(fmax3(t0, t1, t2), t3, t4), sacc[3][3]);         \
        if (__any(mxl > mrow + RESCALE_THR)) {                                             \
            float mx = fmaxf(mxl, __shfl_xor(mxl, 16));                                    \
            mx = fmaxf(mx, __shfl_xor(mx, 32));                                            \
            float mnew = fmaxf(mrow, mx);                                                  \
            float alpha = __builtin_amdgcn_exp2f(mrow - mnew);                             \
            mrow = mnew;                                                                   \
            accL = accL * alpha;                                                           \
            _Pragma("unroll")                                                              \
            for (int nt = 0; nt < 4; ++nt) acc[nt] = acc[nt] * alpha;                      \
        }                                                                                  \
        _Pragma("unroll")                                                                  \
        for (int ct = 0; ct < 4; ++ct)                                                     \
            _Pragma("unroll")                                                              \
            for (int r = 0; r < 4; ++r)                                                    \
                sacc[ct][r] = __builtin_amdgcn_exp2f(sacc[ct][r] - mrow);                  \
        _Pragma("unroll")                                                                  \
        for (int ct = 0; ct < 4; ++ct) {                                                   \
            u32x2 d;                                                                       \
            d[0] = pk2bf(sacc[ct][0], sacc[ct][1]);                                        \
            d[1] = pk2bf(sacc[ct][2], sacc[ct][3]);                                        \
            int blk = 2 * ct + (kg >> 1);                                                  \
            *(u32x2*)&pw[cidx * 64 + ((blk ^ (cidx & 7)) << 3) + (kg & 1) * 4] = d;        \
        }                                                                                  \
        bf16x8 pf0 = ld8(&pw[cidx * 64 + ((kg ^ (cidx & 7)) << 3)]);                       \
        bf16x8 pf1 = ld8(&pw[cidx * 64 + (((4 ^ kg) ^ (cidx & 7)) << 3)]);                 \
        __builtin_amdgcn_s_setprio(1);                                                     \
        _Pragma("unroll")                                                                  \
        for (int nt = 0; nt < 4; ++nt) {                                                   \
            int rr = nt * 16 + cidx;                                                       \
            bf16x8 v0 = ld8(&vb[rr * 64 + ((kg ^ (rr & 7)) << 3)]);                        \
            bf16x8 v1 = ld8(&vb[rr * 64 + (((4 ^ kg) ^ (rr & 7)) << 3)]);                  \
            acc[nt] = __builtin_amdgcn_mfma_f32_16x16x32_bf16(v0, pf0, acc[nt], 0, 0, 0);  \
            acc[nt] = __builtin_amdgcn_mfma_f32_16x16x32_bf16(v1, pf1, acc[nt], 0, 0, 0);  \
        }                                                                                  \
        accL = __builtin_amdgcn_mfma_f32_16x16x32_bf16(onesf, pf0, accL, 0, 0, 0);         \
        accL = __builtin_amdgcn_mfma_f32_16x16x32_bf16(onesf, pf1, accL, 0, 0, 0);         \
        __builtin_amdgcn_s_setprio(0);                                                     \
        __syncthreads();  /* drains gll(buf^1); reads of buf[cur] complete */              \
    }

    for (int it = 0; it < NIT; it += 2) {
        ATTN_TILE(it, 0)
        ATTN_TILE(it + 1, 1)
    }
#undef ATTN_TILE

    // epilogue: L[q] sits in lane q (kg==0), comp 0 — broadcast, normalize, write bf16 Ab.
    float Lb = __shfl(accL[0], cidx);
    float invL = 1.f / Lb;
    const long abase = ((long)(b * S_LEN + q0 + cidx)) * DMODEL + h * DHEAD;
#pragma unroll
    for (int nt = 0; nt < 4; ++nt) {
        u32x2 d;
        d[0] = pk2bf(acc[nt][0] * invL, acc[nt][1] * invL);
        d[1] = pk2bf(acc[nt][2] * invL, acc[nt][3] * invL);
        *(u32x2*)(Ab + abase + nt * 16 + kg * 4) = d;
    }
}

extern "C" void kernel_launch(void* const* d_in, const int* in_sizes, int n_in,
                              void* d_out, int out_size, void* d_ws, size_t ws_size,
                              hipStream_t stream) {
    const float* q_in = (const float*)d_in[0];
    const float* k_in = (const float*)d_in[1];
    const float* v_in = (const float*)d_in[2];
    const float* mask = (const float*)d_in[3];
    const float* wq = (const float*)d_in[4];
    const float* bq = (const float*)d_in[5];
    const float* wk = (const float*)d_in[6];
    const float* bk = (const float*)d_in[7];
    const float* wv = (const float*)d_in[8];
    const float* bv = (const float*)d_in[9];
    const float* wo = (const float*)d_in[10];
    const float* bo = (const float*)d_in[11];

    // ws layout (u16 units):
    u16* ws = (u16*)d_ws;
    u16* Qb = ws;                       // 2.1M  projected Q (pre-scaled QSCALE)
    u16* Kb = Qb + 2097152;             // 2.1M
    u16* Vt = Kb + 2097152;             // 2.1M  V transposed (B,H,DH,S) - written by qkv_gemm
    u16* wtall = Vt + 2097152;          // 4 x 262144: [wo, wq, wk, wv]
    u16* Sreg = wtall + 4 * 262144;     // 3 x 2.1M: Aq,Ak,Av  (dead after qkv_gemm)
    u16* Ab = Sreg + 3 * 2097152;       // 2.1M  attention output (merged heads)
    int* mflags = (int*)(Ab + 2097152); // 2048 ints

    prep_kernel<<<6144, 256, 0, stream>>>(q_in, k_in, v_in, wq, wk, wv, wo, mask,
                                          Sreg, wtall, mflags);
    qkv_gemm_kernel<<<dim3(8, 32, 3), 256, 0, stream>>>(Sreg, wtall, bq, bk, bv, Qb, Kb, Vt);
    attn_kernel<<<dim3(32, 16), 256, 0, stream>>>(Qb, Kb, Vt, mask, mflags, Ab);
    out_gemm_kernel<<<dim3(8, 128), 256, 0, stream>>>(Ab, wtall, bo, (float*)d_out);
}